// Round 6
// baseline (454.527 us; speedup 1.0000x reference)
//
#include <hip/hip_runtime.h>
#include <hip/hip_bf16.h>

#define EMB_D 128
#define BSH 9          // rows per coarse bucket = 512
#define MAXBUCK 512    // nbuck = ceil(N/512) must be <= 512 (N <= 262144)
#define CHUNKP 4096    // edges per partition block

typedef float f32x2 __attribute__((ext_vector_type(2)));

__device__ __forceinline__ float bf16_raw_to_f(unsigned short h) {
    return __uint_as_float(((unsigned int)h) << 16);
}
__device__ __forceinline__ float sane(float v) {
    return (v == v && fabsf(v) < 256.0f) ? v : 0.0f;
}
__device__ __forceinline__ float load_f(const void* p, int isf32, size_t idx) {
    return isf32 ? ((const float*)p)[idx]
                 : bf16_raw_to_f(((const unsigned short*)p)[idx]);
}

// ---------- fp8 e4m3fn via guaranteed gfx950 HW converts (inline asm) ------
// decode 2 fp8 (low 16 bits of w) -> 2 f32
__device__ __forceinline__ f32x2 cvt2_fp8(unsigned int w) {
    f32x2 r;
    asm("v_cvt_pk_f32_fp8 %0, %1" : "=v"(r) : "v"(w));
    return r;
}
// encode 2 f32 -> 2 fp8 bytes in D[15:0] (upper bits undefined -> mask)
__device__ __forceinline__ unsigned int enc2_fp8(float a, float b) {
    unsigned int r;
    asm("v_cvt_pk_fp8_f32 %0, %1, %2" : "=v"(r) : "v"(a), "v"(b));
    return r & 0xFFFFu;
}
__device__ __forceinline__ unsigned int fp8x4_enc(float a, float b, float c, float d) {
    return enc2_fp8(a, b) | (enc2_fp8(c, d) << 16);
}
__device__ __forceinline__ float fp8_dec_byte(unsigned int b) {
    return cvt2_fp8(b & 0xFFu).x;
}

// flags[a]=1 if array a is stored fp32, 0 if bf16 (insurance; expect all 1).
__global__ void k_detect(const unsigned short* __restrict__ ue,
                         const unsigned short* __restrict__ ie,
                         const unsigned short* __restrict__ ev,
                         int* __restrict__ flags) {
    int a = blockIdx.x;
    const unsigned short* p = (a == 0) ? ue : (a == 1) ? ie : ev;
    int lane = threadIdx.x;
    int cnt = 0;
    #pragma unroll
    for (int k = 0; k < 16; ++k) {
        float v = bf16_raw_to_f(p[k * 64 + lane]);
        if (!(fabsf(v) < 1.0f)) cnt++;
    }
    #pragma unroll
    for (int off = 32; off > 0; off >>= 1)
        cnt += __shfl_down(cnt, off, 64);
    if (lane == 0) flags[a] = (cnt > 64) ? 1 : 0;
}

// Canonical fp8 table T[N,128] + per-row scale S[N]. 32 lanes per row.
__global__ __launch_bounds__(256) void k_build_emb8(
        const void* __restrict__ ue, const void* __restrict__ ie,
        const int* __restrict__ flags,
        unsigned char* __restrict__ T, float* __restrict__ S,
        int NU, int N) {
    int gid = blockIdx.x * blockDim.x + threadIdx.x;
    int row = gid >> 5;
    if (row >= N) return;
    int l = gid & 31;
    const void* src; long r; int f;
    if (row < NU) { src = ue; r = row;      f = flags[0]; }
    else          { src = ie; r = row - NU; f = flags[1]; }
    float v0, v1, v2, v3;
    if (f) {
        float4 t = ((const float4*)src)[r * 32 + l];
        v0 = sane(t.x); v1 = sane(t.y); v2 = sane(t.z); v3 = sane(t.w);
    } else {
        ushort4 t = ((const ushort4*)src)[r * 32 + l];
        v0 = sane(bf16_raw_to_f(t.x)); v1 = sane(bf16_raw_to_f(t.y));
        v2 = sane(bf16_raw_to_f(t.z)); v3 = sane(bf16_raw_to_f(t.w));
    }
    float m = fmaxf(fmaxf(fabsf(v0), fabsf(v1)), fmaxf(fabsf(v2), fabsf(v3)));
    #pragma unroll
    for (int off = 1; off < 32; off <<= 1)
        m = fmaxf(m, __shfl_xor(m, off, 64));
    float enc = (m > 0.0f) ? 448.0f / m : 0.0f;
    ((unsigned int*)T)[(size_t)row * 32 + l] =
        fp8x4_enc(v0 * enc, v1 * enc, v2 * enc, v3 * enc);
    if (l == 0) S[row] = (m > 0.0f) ? m * (1.0f / 448.0f) : 0.0f;
}

// Layer-0 gather (fp32 from ORIGINAL inputs) into accumulators.
__global__ void k_init_acc(const void* __restrict__ ue, const void* __restrict__ ie,
                           const int* __restrict__ flags,
                           const int* __restrict__ user, const int* __restrict__ pos,
                           const int* __restrict__ neg, int NU, int NI,
                           float* __restrict__ uacc, float* __restrict__ pacc,
                           float* __restrict__ nacc, float* __restrict__ regp) {
    __shared__ float sred[2];
    int b = blockIdx.x;
    int d = threadIdx.x;   // 0..127
    int ui = min(max(user[b], 0), NU - 1);
    int pi = min(max(pos[b],  0), NI - 1);
    int ni = min(max(neg[b],  0), NI - 1);
    int f0 = flags[0], f1 = flags[1];
    float u = sane(load_f(ue, f0, (size_t)ui * EMB_D + d));
    float p = sane(load_f(ie, f1, (size_t)pi * EMB_D + d));
    float n = sane(load_f(ie, f1, (size_t)ni * EMB_D + d));
    size_t o = (size_t)b * EMB_D + d;
    uacc[o] = u;
    pacc[o] = p;
    nacc[o] = n;
    float s = fabsf(u) + fabsf(p) + fabsf(n);
    #pragma unroll
    for (int off = 32; off > 0; off >>= 1)
        s += __shfl_down(s, off, 64);
    if ((d & 63) == 0) sred[d >> 6] = s;
    __syncthreads();
    if (d == 0) regp[b] = sred[0] + sred[1];
}

// Reduce regp[B] -> reg[0]. Single block.
__global__ void k_reduce_reg(const float* __restrict__ regp, float* __restrict__ reg, int B) {
    __shared__ float ss[256];
    int t = threadIdx.x;
    float s = 0.0f;
    for (int i = t; i < B; i += 256) s += regp[i];
    ss[t] = s;
    __syncthreads();
    for (int off = 128; off > 0; off >>= 1) {
        if (t < off) ss[t] += ss[t + off];
        __syncthreads();
    }
    if (t == 0) reg[0] = ss[0];
}

// ---------- CSR build, transaction-efficient two-level partition ----------

__global__ __launch_bounds__(256) void k_part_count(const int* __restrict__ erow,
        int* __restrict__ bcnt, int E, int N, int nbuck, int NB) {
    __shared__ int lh[MAXBUCK];
    int b = blockIdx.x, t = threadIdx.x;
    for (int i = t; i < MAXBUCK; i += 256) lh[i] = 0;
    __syncthreads();
    int beg = b * CHUNKP;
    int cnt = min(CHUNKP, E - beg);
    for (int p = t; p < cnt; p += 256) {
        int r = min(max(erow[beg + p], 0), N - 1);
        atomicAdd(&lh[r >> BSH], 1);
    }
    __syncthreads();
    for (int i = t; i < nbuck; i += 256) bcnt[(long)i * NB + b] = lh[i];
}

// Generic 3-phase exclusive scan over int array a[L] (in place).
__global__ void k_gscan1(const int* __restrict__ a, int* __restrict__ bsums, int L) {
    __shared__ int ss[256];
    int t = threadIdx.x;
    int base = blockIdx.x * 1024 + t * 4;
    int s = 0;
    #pragma unroll
    for (int j = 0; j < 4; ++j) {
        int idx = base + j;
        if (idx < L) s += a[idx];
    }
    ss[t] = s;
    __syncthreads();
    for (int off = 128; off > 0; off >>= 1) {
        if (t < off) ss[t] += ss[t + off];
        __syncthreads();
    }
    if (t == 0) bsums[blockIdx.x] = ss[0];
}

__global__ void k_gscan2(const int* __restrict__ bsums, int* __restrict__ boffs,
                         int nb, int* __restrict__ rowptrN) {
    __shared__ int ss[256];
    int t = threadIdx.x;
    int s = (t < nb) ? bsums[t] : 0;
    ss[t] = s;
    __syncthreads();
    for (int off = 1; off < 256; off <<= 1) {
        int v = (t >= off) ? ss[t - off] : 0;
        __syncthreads();
        ss[t] += v;
        __syncthreads();
    }
    if (t < nb) boffs[t] = ss[t] - s;       // exclusive
    if (t == 255) *rowptrN = ss[255];       // total E -> row_ptr[N]
}

__global__ void k_gscan3(int* __restrict__ a, const int* __restrict__ boffs, int L) {
    __shared__ int ss[256];
    int t = threadIdx.x;
    int base = blockIdx.x * 1024 + t * 4;
    int c[4];
    int s = 0;
    #pragma unroll
    for (int j = 0; j < 4; ++j) {
        int idx = base + j;
        c[j] = (idx < L) ? a[idx] : 0;
        s += c[j];
    }
    ss[t] = s;
    __syncthreads();
    for (int off = 1; off < 256; off <<= 1) {
        int v = (t >= off) ? ss[t - off] : 0;
        __syncthreads();
        ss[t] += v;
        __syncthreads();
    }
    int run = boffs[blockIdx.x] + ss[t] - s;
    #pragma unroll
    for (int j = 0; j < 4; ++j) {
        int idx = base + j;
        if (idx < L) a[idx] = run;
        run += c[j];
    }
}

__global__ __launch_bounds__(256) void k_part_scatter(
        const int* __restrict__ erow, const int* __restrict__ ecol,
        const void* __restrict__ eval, const int* __restrict__ flags,
        const int* __restrict__ boff, uint2* __restrict__ part,
        int E, int N, int nbuck, int NB) {
    __shared__ uint2 lrec[CHUNKP];            // 32 KB
    __shared__ unsigned short lidx[CHUNKP];   // 8 KB
    __shared__ int hist[MAXBUCK];             // 2 KB (hist -> cursor -> delta)
    __shared__ int bstart[MAXBUCK];           // 2 KB
    __shared__ int ss[256];
    int b = blockIdx.x, t = threadIdx.x;
    int beg = b * CHUNKP;
    int cnt = min(CHUNKP, E - beg);
    for (int i = t; i < MAXBUCK; i += 256) hist[i] = 0;
    __syncthreads();
    int f2 = flags[2];
    for (int p = t; p < cnt; p += 256) {
        int e = beg + p;
        int r = min(max(erow[e], 0), N - 1);
        int c = min(max(ecol[e], 0), N - 1);
        float v = sane(load_f(eval, f2, e));
        if (v < 0.0f) v = 0.0f;
        unsigned int u = __float_as_uint(v);
        unsigned int vb = ((u + 0x10000u) >> 17) & 0x3FFFu;   // exp8 + man6
        lrec[p] = make_uint2((unsigned int)r, ((unsigned int)c << 14) | vb);
        atomicAdd(&hist[r >> BSH], 1);
    }
    __syncthreads();
    int c0 = hist[2 * t], c1 = hist[2 * t + 1];
    int s = c0 + c1;
    ss[t] = s;
    __syncthreads();
    for (int off = 1; off < 256; off <<= 1) {
        int v = (t >= off) ? ss[t - off] : 0;
        __syncthreads();
        ss[t] += v;
        __syncthreads();
    }
    int eb = ss[t] - s;
    bstart[2 * t] = eb;
    bstart[2 * t + 1] = eb + c0;
    hist[2 * t] = eb;              // cursor = bstart
    hist[2 * t + 1] = eb + c0;
    __syncthreads();
    for (int p = t; p < cnt; p += 256) {
        int bin = (int)(lrec[p].x >> BSH);
        int pos = atomicAdd(&hist[bin], 1);
        lidx[pos] = (unsigned short)p;
    }
    __syncthreads();
    for (int i = t; i < nbuck; i += 256)
        hist[i] = boff[(long)i * NB + b] - bstart[i];
    __syncthreads();
    for (int p = t; p < cnt; p += 256) {
        uint2 rec = lrec[lidx[p]];
        int bin = (int)(rec.x >> BSH);
        part[hist[bin] + p] = rec;
    }
}

__global__ __launch_bounds__(256) void k_build_csr(
        const uint2* __restrict__ part, const int* __restrict__ boff,
        int* __restrict__ row_ptr, unsigned int* __restrict__ sedge,
        int E, int N, int NB, int nbuck) {
    __shared__ int rcnt[512];
    __shared__ int rstart[512];
    __shared__ int rcur[512];
    __shared__ int ss[256];
    int bin = blockIdx.x, t = threadIdx.x;
    int base = boff[(long)bin * NB];
    int next = (bin + 1 < nbuck) ? boff[(long)(bin + 1) * NB] : E;
    int cnt = next - base;
    int r0 = bin << BSH;
    int nrows = min(512, N - r0);
    rcnt[2 * t] = 0; rcnt[2 * t + 1] = 0;
    __syncthreads();
    for (int i = t; i < cnt; i += 256)
        atomicAdd(&rcnt[part[base + i].x - r0], 1);
    __syncthreads();
    int c0 = rcnt[2 * t], c1 = rcnt[2 * t + 1];
    int s = c0 + c1;
    ss[t] = s;
    __syncthreads();
    for (int off = 1; off < 256; off <<= 1) {
        int v = (t >= off) ? ss[t - off] : 0;
        __syncthreads();
        ss[t] += v;
        __syncthreads();
    }
    int eb = ss[t] - s;
    rstart[2 * t] = eb; rstart[2 * t + 1] = eb + c0;
    rcur[2 * t]   = eb; rcur[2 * t + 1]   = eb + c0;
    __syncthreads();
    for (int j = t; j < nrows; j += 256)
        row_ptr[r0 + j] = base + rstart[j];
    for (int i = t; i < cnt; i += 256) {
        uint2 rec = part[base + i];
        int pos = atomicAdd(&rcur[rec.x - r0], 1);
        sedge[base + pos] = rec.y;
    }
}

// ---------- Frontier marking (backward pruning, bit-exact) ----------

__global__ void k_zero_flags(int* __restrict__ f, int words) {
    int i = blockIdx.x * blockDim.x + threadIdx.x;
    if (i < words) f[i] = 0;
}

__global__ void k_mark_batch(const int* __restrict__ user, const int* __restrict__ pos,
                             const int* __restrict__ neg, int NU, int NI, int B,
                             unsigned char* __restrict__ flag3,
                             unsigned char* __restrict__ flag2) {
    int b = blockIdx.x * blockDim.x + threadIdx.x;
    if (b >= B) return;
    int ui = min(max(user[b], 0), NU - 1);
    int pi = NU + min(max(pos[b], 0), NI - 1);
    int ni = NU + min(max(neg[b], 0), NI - 1);
    flag3[ui] = 1; flag3[pi] = 1; flag3[ni] = 1;
    flag2[ui] = 1; flag2[pi] = 1; flag2[ni] = 1;
}

__global__ void k_mark_nbrs(const int* __restrict__ row_ptr,
                            const unsigned int* __restrict__ sedge,
                            const unsigned char* __restrict__ flag3,
                            unsigned char* __restrict__ flag2, int N) {
    int r = blockIdx.x * blockDim.x + threadIdx.x;
    if (r >= N || !flag3[r]) return;
    int beg = row_ptr[r], end = row_ptr[r + 1];
    for (int i = beg; i < end; ++i)
        flag2[sedge[i] >> 14] = 1;
}

// ---------- SpMM (fp8 in / fp8 out, per-row scales) + tail ----------

// One wave per dst row; 8 subgroups of 8 lanes each process every 8th edge;
// lane sl covers fp8 bytes [16*sl, 16*sl+15] (one uint4) of the 128B row.
// Edge loop is unrolled by 2 for MLP (both gathers issued together).
__global__ void k_spmm_csr8(const unsigned char* __restrict__ T,
                            const float* __restrict__ S,
                            unsigned char* __restrict__ Td,
                            float* __restrict__ Sd,
                            const int* __restrict__ row_ptr,
                            const unsigned int* __restrict__ sedge, int N,
                            const unsigned char* __restrict__ skipf, int use_skip) {
    int row = blockIdx.x * (blockDim.x >> 6) + (threadIdx.x >> 6);
    if (row >= N) return;
    if (use_skip && skipf[row] == 0) return;
    int lane = threadIdx.x & 63;
    int sub = lane >> 3;         // 0..7: edge phase
    int sl  = lane & 7;          // 16B chunk of the row
    int beg = row_ptr[row], end = row_ptr[row + 1];
    float a[16];
    #pragma unroll
    for (int j = 0; j < 16; ++j) a[j] = 0.0f;
    int i = beg + sub;
    // pair loop: edges i and i+8 in flight together
    for (; i + 8 < end; i += 16) {
        unsigned int se0 = sedge[i];
        unsigned int se1 = sedge[i + 8];
        unsigned int c0 = se0 >> 14, c1 = se1 >> 14;
        uint4 h0 = ((const uint4*)(T + (size_t)c0 * EMB_D))[sl];
        uint4 h1 = ((const uint4*)(T + (size_t)c1 * EMB_D))[sl];
        float vs0 = __uint_as_float((se0 & 0x3FFFu) << 17) * S[c0];
        float vs1 = __uint_as_float((se1 & 0x3FFFu) << 17) * S[c1];
        f32x2 d;
        d = cvt2_fp8(h0.x);       a[0] += vs0 * d.x;  a[1] += vs0 * d.y;
        d = cvt2_fp8(h0.x >> 16); a[2] += vs0 * d.x;  a[3] += vs0 * d.y;
        d = cvt2_fp8(h0.y);       a[4] += vs0 * d.x;  a[5] += vs0 * d.y;
        d = cvt2_fp8(h0.y >> 16); a[6] += vs0 * d.x;  a[7] += vs0 * d.y;
        d = cvt2_fp8(h0.z);       a[8] += vs0 * d.x;  a[9] += vs0 * d.y;
        d = cvt2_fp8(h0.z >> 16); a[10] += vs0 * d.x; a[11] += vs0 * d.y;
        d = cvt2_fp8(h0.w);       a[12] += vs0 * d.x; a[13] += vs0 * d.y;
        d = cvt2_fp8(h0.w >> 16); a[14] += vs0 * d.x; a[15] += vs0 * d.y;
        d = cvt2_fp8(h1.x);       a[0] += vs1 * d.x;  a[1] += vs1 * d.y;
        d = cvt2_fp8(h1.x >> 16); a[2] += vs1 * d.x;  a[3] += vs1 * d.y;
        d = cvt2_fp8(h1.y);       a[4] += vs1 * d.x;  a[5] += vs1 * d.y;
        d = cvt2_fp8(h1.y >> 16); a[6] += vs1 * d.x;  a[7] += vs1 * d.y;
        d = cvt2_fp8(h1.z);       a[8] += vs1 * d.x;  a[9] += vs1 * d.y;
        d = cvt2_fp8(h1.z >> 16); a[10] += vs1 * d.x; a[11] += vs1 * d.y;
        d = cvt2_fp8(h1.w);       a[12] += vs1 * d.x; a[13] += vs1 * d.y;
        d = cvt2_fp8(h1.w >> 16); a[14] += vs1 * d.x; a[15] += vs1 * d.y;
    }
    if (i < end) {
        unsigned int se = sedge[i];
        unsigned int c = se >> 14;
        uint4 h = ((const uint4*)(T + (size_t)c * EMB_D))[sl];
        float vs = __uint_as_float((se & 0x3FFFu) << 17) * S[c];
        f32x2 d;
        d = cvt2_fp8(h.x);       a[0] += vs * d.x;  a[1] += vs * d.y;
        d = cvt2_fp8(h.x >> 16); a[2] += vs * d.x;  a[3] += vs * d.y;
        d = cvt2_fp8(h.y);       a[4] += vs * d.x;  a[5] += vs * d.y;
        d = cvt2_fp8(h.y >> 16); a[6] += vs * d.x;  a[7] += vs * d.y;
        d = cvt2_fp8(h.z);       a[8] += vs * d.x;  a[9] += vs * d.y;
        d = cvt2_fp8(h.z >> 16); a[10] += vs * d.x; a[11] += vs * d.y;
        d = cvt2_fp8(h.w);       a[12] += vs * d.x; a[13] += vs * d.y;
        d = cvt2_fp8(h.w >> 16); a[14] += vs * d.x; a[15] += vs * d.y;
    }
    #pragma unroll
    for (int j = 0; j < 16; ++j) {
        a[j] += __shfl_xor(a[j], 8, 64);
        a[j] += __shfl_xor(a[j], 16, 64);
        a[j] += __shfl_xor(a[j], 32, 64);
    }
    // row absmax (a[] identical across subgroups; xor over sl bits 0..2)
    float m = 0.0f;
    #pragma unroll
    for (int j = 0; j < 16; ++j) m = fmaxf(m, fabsf(a[j]));
    m = fmaxf(m, __shfl_xor(m, 1, 64));
    m = fmaxf(m, __shfl_xor(m, 2, 64));
    m = fmaxf(m, __shfl_xor(m, 4, 64));
    if (sub == 0) {
        float enc = (m > 0.0f) ? 448.0f / m : 0.0f;
        uint4 w;
        w.x = fp8x4_enc(a[0] * enc,  a[1] * enc,  a[2] * enc,  a[3] * enc);
        w.y = fp8x4_enc(a[4] * enc,  a[5] * enc,  a[6] * enc,  a[7] * enc);
        w.z = fp8x4_enc(a[8] * enc,  a[9] * enc,  a[10] * enc, a[11] * enc);
        w.w = fp8x4_enc(a[12] * enc, a[13] * enc, a[14] * enc, a[15] * enc);
        ((uint4*)(Td + (size_t)row * EMB_D))[sl] = w;
        if (lane == 0) Sd[row] = (m > 0.0f) ? m * (1.0f / 448.0f) : 0.0f;
    }
}

// Accumulate this layer's rows (fp8 table + scale) at batch indices.
__global__ void k_gather_add8(const unsigned char* __restrict__ T,
                              const float* __restrict__ S,
                              const int* __restrict__ user, const int* __restrict__ pos,
                              const int* __restrict__ neg,
                              float* __restrict__ uacc, float* __restrict__ pacc,
                              float* __restrict__ nacc, int NU, int NI) {
    int b = blockIdx.x;
    int d = threadIdx.x;   // 0..127
    int ui = min(max(user[b], 0), NU - 1);
    int pi = NU + min(max(pos[b], 0), NI - 1);
    int ni = NU + min(max(neg[b], 0), NI - 1);
    size_t o = (size_t)b * EMB_D + d;
    uacc[o] += fp8_dec_byte(T[(size_t)ui * EMB_D + d]) * S[ui];
    pacc[o] += fp8_dec_byte(T[(size_t)pi * EMB_D + d]) * S[pi];
    nacc[o] += fp8_dec_byte(T[(size_t)ni * EMB_D + d]) * S[ni];
}

// One wave per batch element: dots, softplus, + reg; fp32 store.
__global__ void k_final(const float* __restrict__ uacc, const float* __restrict__ pacc,
                        const float* __restrict__ nacc, const float* __restrict__ reg,
                        float* __restrict__ out) {
    int b = blockIdx.x;
    int l = threadIdx.x;   // 0..63
    const float2* u2 = (const float2*)(uacc + (size_t)b * EMB_D);
    const float2* p2 = (const float2*)(pacc + (size_t)b * EMB_D);
    const float2* n2 = (const float2*)(nacc + (size_t)b * EMB_D);
    float2 u = u2[l], p = p2[l], n = n2[l];
    float ps = u.x * p.x + u.y * p.y;
    float ns = u.x * n.x + u.y * n.y;
    #pragma unroll
    for (int off = 32; off > 0; off >>= 1) {
        ps += __shfl_down(ps, off, 64);
        ns += __shfl_down(ns, off, 64);
    }
    if (l == 0) {
        // latents are acc/4 -> scores scale by 1/16
        float x = (ns - ps) * 0.0625f;
        float sp = fmaxf(x, 0.0f) + log1pf(expf(-fabsf(x)));
        out[b] = sp + 1e-4f * reg[0];
    }
}

extern "C" void kernel_launch(void* const* d_in, const int* in_sizes, int n_in,
                              void* d_out, int out_size, void* d_ws, size_t ws_size,
                              hipStream_t stream) {
    const void* ue   = d_in[0];
    const void* ie   = d_in[1];
    const int*  erow = (const int*)d_in[2];
    const int*  ecol = (const int*)d_in[3];
    const void* ev   = d_in[4];
    const int*  user = (const int*)d_in[5];
    const int*  pos  = (const int*)d_in[6];
    const int*  neg  = (const int*)d_in[7];

    int NU = in_sizes[0] / EMB_D;        // 100000
    int NI = in_sizes[1] / EMB_D;        // 50000
    int N  = NU + NI;                    // 150000
    int E  = in_sizes[2];                // 2000000
    int B  = in_sizes[5];                // 8192

    int nbuck = (N + ((1 << BSH) - 1)) >> BSH;   // 293 (must be <= MAXBUCK)
    int NBp   = (E + CHUNKP - 1) / CHUNKP;       // 489 partition blocks
    int L     = nbuck * NBp;                     // 143277
    int nbL   = (L + 1023) / 1024;               // 140 (<= 256)

    // Workspace layout (all 16B-aligned):
    size_t BACC = (size_t)B * EMB_D * sizeof(float);           // 4 MB
    size_t T8   = (size_t)N * EMB_D;                           // 19.2 MB (fp8)
    size_t SC   = (((size_t)N * sizeof(float)) + 15) & ~15ull; // 600 KB
    size_t NI4  = ((size_t)(N + 1) * sizeof(int) + 15) & ~15ull;
    size_t L4   = ((size_t)L * sizeof(int) + 15) & ~15ull;
    size_t Npad = ((size_t)N + 15) & ~15ull;
    char* w = (char*)d_ws;
    int*   flags   = (int*)w;                        // 3 ints
    float* reg     = (float*)(w + 64);               // 1 float
    float* uacc    = (float*)(w + 256);
    float* pacc    = (float*)(w + 256 + BACC);
    float* nacc    = (float*)(w + 256 + 2 * BACC);
    char*  q       = w + 256 + 3 * BACC;
    float* regp    = (float*)q;             q += (size_t)B * sizeof(float);
    int*   row_ptr = (int*)q;               q += NI4;
    uint2* part    = (uint2*)q;             q += (size_t)E * sizeof(uint2);   // 16 MB
    int*   bcnt    = (int*)q;               q += L4;                          // 573 KB
    int*   bsums   = (int*)q;               q += 1024;
    int*   boffs   = (int*)q;               q += 1024;
    unsigned char* flag3 = (unsigned char*)q; q += Npad;                      // 150 KB
    unsigned char* flag2 = (unsigned char*)q; q += Npad;                      // 150 KB
    unsigned int* sedge = (unsigned int*)q; q += (size_t)E * sizeof(unsigned int); // 8 MB
    unsigned char* Ta = (unsigned char*)q;  q += T8;
    float*         Sa = (float*)q;          q += SC;
    unsigned char* Tb = (unsigned char*)q;  q += T8;
    float*         Sb = (float*)q;
    // total ~78 MB (prev session proved ws >= 166 MB)

    const int thr = 256;
    float* out = (float*)d_out;

    k_detect<<<3, 64, 0, stream>>>((const unsigned short*)ue, (const unsigned short*)ie,
                                   (const unsigned short*)ev, flags);
    k_build_emb8<<<(N * 32 + thr - 1) / thr, thr, 0, stream>>>(ue, ie, flags, Ta, Sa, NU, N);
    k_init_acc<<<B, EMB_D, 0, stream>>>(ue, ie, flags, user, pos, neg, NU, NI,
                                        uacc, pacc, nacc, regp);
    k_reduce_reg<<<1, 256, 0, stream>>>(regp, reg, B);

    // Frontier flags: flag3 = batch nodes; flag2 = batch + in-nbrs of flag3.
    int fwords = (int)((2 * Npad) / 4);
    k_zero_flags<<<(fwords + thr - 1) / thr, thr, 0, stream>>>((int*)flag3, fwords);
    k_mark_batch<<<(B + thr - 1) / thr, thr, 0, stream>>>(user, pos, neg, NU, NI, B,
                                                          flag3, flag2);

    // CSR build: two-level LDS partition, no global atomics.
    k_part_count<<<NBp, 256, 0, stream>>>(erow, bcnt, E, N, nbuck, NBp);
    k_gscan1<<<nbL, 256, 0, stream>>>(bcnt, bsums, L);
    k_gscan2<<<1, 256, 0, stream>>>(bsums, boffs, nbL, row_ptr + N);
    k_gscan3<<<nbL, 256, 0, stream>>>(bcnt, boffs, L);
    k_part_scatter<<<NBp, 256, 0, stream>>>(erow, ecol, ev, flags, bcnt, part, E, N, nbuck, NBp);
    k_build_csr<<<nbuck, 256, 0, stream>>>(part, bcnt, row_ptr, sedge, E, N, NBp, nbuck);

    // flag2 |= in-neighbors of flag3 rows (needs CSR).
    k_mark_nbrs<<<(N + thr - 1) / thr, thr, 0, stream>>>(row_ptr, sedge, flag3, flag2, N);

    int rows_per_block = thr / 64;                       // 4
    int sgrid = (N + rows_per_block - 1) / rows_per_block;  // 37500

    // Layer 1: Ta -> Tb (full)
    k_spmm_csr8<<<sgrid, thr, 0, stream>>>(Ta, Sa, Tb, Sb, row_ptr, sedge, N, flag2, 0);
    k_gather_add8<<<B, EMB_D, 0, stream>>>(Tb, Sb, user, pos, neg, uacc, pacc, nacc, NU, NI);
    // Layer 2: Tb -> Ta (rows needed by layer 3 + batch)
    k_spmm_csr8<<<sgrid, thr, 0, stream>>>(Tb, Sb, Ta, Sa, row_ptr, sedge, N, flag2, 1);
    k_gather_add8<<<B, EMB_D, 0, stream>>>(Ta, Sa, user, pos, neg, uacc, pacc, nacc, NU, NI);
    // Layer 3: Ta -> Tb (batch rows only)
    k_spmm_csr8<<<sgrid, thr, 0, stream>>>(Ta, Sa, Tb, Sb, row_ptr, sedge, N, flag3, 1);
    k_gather_add8<<<B, EMB_D, 0, stream>>>(Tb, Sb, user, pos, neg, uacc, pacc, nacc, NU, NI);

    k_final<<<B, 64, 0, stream>>>(uacc, pacc, nacc, reg, out);
}

// Round 7
// 441.455 us; speedup vs baseline: 1.0296x; 1.0296x over previous
//
#include <hip/hip_runtime.h>
#include <hip/hip_bf16.h>

#define EMB_D 128
#define BSH 9          // rows per coarse bucket = 512
#define MAXBUCK 512    // nbuck = ceil(N/512) must be <= 512 (N <= 262144)
#define CHUNKP 2048    // edges per partition block (25 KB LDS -> ~6 blocks/CU)

typedef float f32x2 __attribute__((ext_vector_type(2)));

__device__ __forceinline__ float bf16_raw_to_f(unsigned short h) {
    return __uint_as_float(((unsigned int)h) << 16);
}
__device__ __forceinline__ float sane(float v) {
    return (v == v && fabsf(v) < 256.0f) ? v : 0.0f;
}
__device__ __forceinline__ float load_f(const void* p, int isf32, size_t idx) {
    return isf32 ? ((const float*)p)[idx]
                 : bf16_raw_to_f(((const unsigned short*)p)[idx]);
}

// ---------- fp8 e4m3fn via gfx950 HW converts (inline asm) ------
__device__ __forceinline__ f32x2 cvt2_fp8(unsigned int w) {
    f32x2 r;
    asm("v_cvt_pk_f32_fp8 %0, %1" : "=v"(r) : "v"(w));
    return r;
}
__device__ __forceinline__ unsigned int enc2_fp8(float a, float b) {
    unsigned int r;
    asm("v_cvt_pk_fp8_f32 %0, %1, %2" : "=v"(r) : "v"(a), "v"(b));
    return r & 0xFFFFu;
}
__device__ __forceinline__ unsigned int fp8x4_enc(float a, float b, float c, float d) {
    return enc2_fp8(a, b) | (enc2_fp8(c, d) << 16);
}
__device__ __forceinline__ float fp8_dec_byte(unsigned int b) {
    return cvt2_fp8(b & 0xFFu).x;
}

// flags[a]=1 if array a is stored fp32, 0 if bf16 (insurance; expect all 1).
__global__ void k_detect(const unsigned short* __restrict__ ue,
                         const unsigned short* __restrict__ ie,
                         const unsigned short* __restrict__ ev,
                         int* __restrict__ flags) {
    int a = blockIdx.x;
    const unsigned short* p = (a == 0) ? ue : (a == 1) ? ie : ev;
    int lane = threadIdx.x;
    int cnt = 0;
    #pragma unroll
    for (int k = 0; k < 16; ++k) {
        float v = bf16_raw_to_f(p[k * 64 + lane]);
        if (!(fabsf(v) < 1.0f)) cnt++;
    }
    #pragma unroll
    for (int off = 32; off > 0; off >>= 1)
        cnt += __shfl_down(cnt, off, 64);
    if (lane == 0) flags[a] = (cnt > 64) ? 1 : 0;
}

// Canonical fp8 table T[N,128] + per-row scale S[N]. 32 lanes per row.
__global__ __launch_bounds__(256) void k_build_emb8(
        const void* __restrict__ ue, const void* __restrict__ ie,
        const int* __restrict__ flags,
        unsigned char* __restrict__ T, float* __restrict__ S,
        int NU, int N) {
    int gid = blockIdx.x * blockDim.x + threadIdx.x;
    int row = gid >> 5;
    if (row >= N) return;
    int l = gid & 31;
    const void* src; long r; int f;
    if (row < NU) { src = ue; r = row;      f = flags[0]; }
    else          { src = ie; r = row - NU; f = flags[1]; }
    float v0, v1, v2, v3;
    if (f) {
        float4 t = ((const float4*)src)[r * 32 + l];
        v0 = sane(t.x); v1 = sane(t.y); v2 = sane(t.z); v3 = sane(t.w);
    } else {
        ushort4 t = ((const ushort4*)src)[r * 32 + l];
        v0 = sane(bf16_raw_to_f(t.x)); v1 = sane(bf16_raw_to_f(t.y));
        v2 = sane(bf16_raw_to_f(t.z)); v3 = sane(bf16_raw_to_f(t.w));
    }
    float m = fmaxf(fmaxf(fabsf(v0), fabsf(v1)), fmaxf(fabsf(v2), fabsf(v3)));
    #pragma unroll
    for (int off = 1; off < 32; off <<= 1)
        m = fmaxf(m, __shfl_xor(m, off, 64));
    float enc = (m > 0.0f) ? 448.0f / m : 0.0f;
    ((unsigned int*)T)[(size_t)row * 32 + l] =
        fp8x4_enc(v0 * enc, v1 * enc, v2 * enc, v3 * enc);
    if (l == 0) S[row] = (m > 0.0f) ? m * (1.0f / 448.0f) : 0.0f;
}

// L1-reg partial per batch element (layer-0 only; fp32 from ORIGINAL inputs).
__global__ void k_reg(const void* __restrict__ ue, const void* __restrict__ ie,
                      const int* __restrict__ flags,
                      const int* __restrict__ user, const int* __restrict__ pos,
                      const int* __restrict__ neg, int NU, int NI,
                      float* __restrict__ regp) {
    __shared__ float sred[2];
    int b = blockIdx.x;
    int d = threadIdx.x;   // 0..127
    int ui = min(max(user[b], 0), NU - 1);
    int pi = min(max(pos[b],  0), NI - 1);
    int ni = min(max(neg[b],  0), NI - 1);
    int f0 = flags[0], f1 = flags[1];
    float u = sane(load_f(ue, f0, (size_t)ui * EMB_D + d));
    float p = sane(load_f(ie, f1, (size_t)pi * EMB_D + d));
    float n = sane(load_f(ie, f1, (size_t)ni * EMB_D + d));
    float s = fabsf(u) + fabsf(p) + fabsf(n);
    #pragma unroll
    for (int off = 32; off > 0; off >>= 1)
        s += __shfl_down(s, off, 64);
    if ((d & 63) == 0) sred[d >> 6] = s;
    __syncthreads();
    if (d == 0) regp[b] = sred[0] + sred[1];
}

// Reduce regp[B] -> reg[0]. Single block.
__global__ void k_reduce_reg(const float* __restrict__ regp, float* __restrict__ reg, int B) {
    __shared__ float ss[256];
    int t = threadIdx.x;
    float s = 0.0f;
    for (int i = t; i < B; i += 256) s += regp[i];
    ss[t] = s;
    __syncthreads();
    for (int off = 128; off > 0; off >>= 1) {
        if (t < off) ss[t] += ss[t + off];
        __syncthreads();
    }
    if (t == 0) reg[0] = ss[0];
}

// ---------- CSR build, transaction-efficient two-level partition ----------

__global__ __launch_bounds__(256) void k_part_count(const int* __restrict__ erow,
        int* __restrict__ bcnt, int E, int N, int nbuck, int NB) {
    __shared__ int lh[MAXBUCK];
    int b = blockIdx.x, t = threadIdx.x;
    for (int i = t; i < MAXBUCK; i += 256) lh[i] = 0;
    __syncthreads();
    int beg = b * CHUNKP;
    int cnt = min(CHUNKP, E - beg);
    for (int p = t; p < cnt; p += 256) {
        int r = min(max(erow[beg + p], 0), N - 1);
        atomicAdd(&lh[r >> BSH], 1);
    }
    __syncthreads();
    for (int i = t; i < nbuck; i += 256) bcnt[(long)i * NB + b] = lh[i];
}

// Generic 3-phase exclusive scan over int array a[L] (in place).
__global__ void k_gscan1(const int* __restrict__ a, int* __restrict__ bsums, int L) {
    __shared__ int ss[256];
    int t = threadIdx.x;
    int base = blockIdx.x * 1024 + t * 4;
    int s = 0;
    #pragma unroll
    for (int j = 0; j < 4; ++j) {
        int idx = base + j;
        if (idx < L) s += a[idx];
    }
    ss[t] = s;
    __syncthreads();
    for (int off = 128; off > 0; off >>= 1) {
        if (t < off) ss[t] += ss[t + off];
        __syncthreads();
    }
    if (t == 0) bsums[blockIdx.x] = ss[0];
}

// Single block scans nb (<=1024) block sums, 4 per thread.
__global__ void k_gscan2(const int* __restrict__ bsums, int* __restrict__ boffs,
                         int nb, int* __restrict__ rowptrN) {
    __shared__ int ss[256];
    int t = threadIdx.x;
    int base = t * 4;
    int c[4];
    int s = 0;
    #pragma unroll
    for (int j = 0; j < 4; ++j) {
        c[j] = (base + j < nb) ? bsums[base + j] : 0;
        s += c[j];
    }
    ss[t] = s;
    __syncthreads();
    for (int off = 1; off < 256; off <<= 1) {
        int v = (t >= off) ? ss[t - off] : 0;
        __syncthreads();
        ss[t] += v;
        __syncthreads();
    }
    int run = ss[t] - s;
    #pragma unroll
    for (int j = 0; j < 4; ++j) {
        if (base + j < nb) boffs[base + j] = run;
        run += c[j];
    }
    if (t == 255) *rowptrN = ss[255];       // total E -> row_ptr[N]
}

__global__ void k_gscan3(int* __restrict__ a, const int* __restrict__ boffs, int L) {
    __shared__ int ss[256];
    int t = threadIdx.x;
    int base = blockIdx.x * 1024 + t * 4;
    int c[4];
    int s = 0;
    #pragma unroll
    for (int j = 0; j < 4; ++j) {
        int idx = base + j;
        c[j] = (idx < L) ? a[idx] : 0;
        s += c[j];
    }
    ss[t] = s;
    __syncthreads();
    for (int off = 1; off < 256; off <<= 1) {
        int v = (t >= off) ? ss[t - off] : 0;
        __syncthreads();
        ss[t] += v;
        __syncthreads();
    }
    int run = boffs[blockIdx.x] + ss[t] - s;
    #pragma unroll
    for (int j = 0; j < 4; ++j) {
        int idx = base + j;
        if (idx < L) a[idx] = run;
        run += c[j];
    }
}

// Pass B: counting-sort CHUNKP edges by dst bucket in LDS, stream out
// split records: part_cv (col<<14|val14, u32) + part_r (row & 511, u16).
__global__ __launch_bounds__(256) void k_part_scatter(
        const int* __restrict__ erow, const int* __restrict__ ecol,
        const void* __restrict__ eval, const int* __restrict__ flags,
        const int* __restrict__ boff,
        unsigned int* __restrict__ part_cv, unsigned short* __restrict__ part_r,
        int E, int N, int nbuck, int NB) {
    __shared__ uint2 lrec[CHUNKP];            // 16 KB
    __shared__ unsigned short lidx[CHUNKP];   // 4 KB
    __shared__ int hist[MAXBUCK];             // 2 KB (hist -> cursor -> delta)
    __shared__ int bstart[MAXBUCK];           // 2 KB
    __shared__ int ss[256];
    int b = blockIdx.x, t = threadIdx.x;
    int beg = b * CHUNKP;
    int cnt = min(CHUNKP, E - beg);
    for (int i = t; i < MAXBUCK; i += 256) hist[i] = 0;
    __syncthreads();
    int f2 = flags[2];
    for (int p = t; p < cnt; p += 256) {
        int e = beg + p;
        int r = min(max(erow[e], 0), N - 1);
        int c = min(max(ecol[e], 0), N - 1);
        float v = sane(load_f(eval, f2, e));
        if (v < 0.0f) v = 0.0f;
        unsigned int u = __float_as_uint(v);
        unsigned int vb = ((u + 0x10000u) >> 17) & 0x3FFFu;   // exp8 + man6
        lrec[p] = make_uint2((unsigned int)r, ((unsigned int)c << 14) | vb);
        atomicAdd(&hist[r >> BSH], 1);
    }
    __syncthreads();
    int c0 = hist[2 * t], c1 = hist[2 * t + 1];
    int s = c0 + c1;
    ss[t] = s;
    __syncthreads();
    for (int off = 1; off < 256; off <<= 1) {
        int v = (t >= off) ? ss[t - off] : 0;
        __syncthreads();
        ss[t] += v;
        __syncthreads();
    }
    int eb = ss[t] - s;
    bstart[2 * t] = eb;
    bstart[2 * t + 1] = eb + c0;
    hist[2 * t] = eb;              // cursor = bstart
    hist[2 * t + 1] = eb + c0;
    __syncthreads();
    for (int p = t; p < cnt; p += 256) {
        int bin = (int)(lrec[p].x >> BSH);
        int pos = atomicAdd(&hist[bin], 1);
        lidx[pos] = (unsigned short)p;
    }
    __syncthreads();
    for (int i = t; i < nbuck; i += 256)
        hist[i] = boff[(long)i * NB + b] - bstart[i];
    __syncthreads();
    for (int p = t; p < cnt; p += 256) {
        uint2 rec = lrec[lidx[p]];
        int bin = (int)(rec.x >> BSH);
        int o = hist[bin] + p;
        part_cv[o] = rec.y;
        part_r[o] = (unsigned short)(rec.x & 511u);
    }
}

// Pass C: one block per bucket (<=512 rows, L2-resident window).
__global__ __launch_bounds__(256) void k_build_csr(
        const unsigned int* __restrict__ part_cv,
        const unsigned short* __restrict__ part_r,
        const int* __restrict__ boff,
        int* __restrict__ row_ptr, unsigned int* __restrict__ sedge,
        int E, int N, int NB, int nbuck) {
    __shared__ int rcnt[512];
    __shared__ int rstart[512];
    __shared__ int rcur[512];
    __shared__ int ss[256];
    int bin = blockIdx.x, t = threadIdx.x;
    int base = boff[(long)bin * NB];
    int next = (bin + 1 < nbuck) ? boff[(long)(bin + 1) * NB] : E;
    int cnt = next - base;
    int r0 = bin << BSH;
    int nrows = min(512, N - r0);
    rcnt[2 * t] = 0; rcnt[2 * t + 1] = 0;
    __syncthreads();
    for (int i = t; i < cnt; i += 256)
        atomicAdd(&rcnt[part_r[base + i]], 1);
    __syncthreads();
    int c0 = rcnt[2 * t], c1 = rcnt[2 * t + 1];
    int s = c0 + c1;
    ss[t] = s;
    __syncthreads();
    for (int off = 1; off < 256; off <<= 1) {
        int v = (t >= off) ? ss[t - off] : 0;
        __syncthreads();
        ss[t] += v;
        __syncthreads();
    }
    int eb = ss[t] - s;
    rstart[2 * t] = eb; rstart[2 * t + 1] = eb + c0;
    rcur[2 * t]   = eb; rcur[2 * t + 1]   = eb + c0;
    __syncthreads();
    for (int j = t; j < nrows; j += 256)
        row_ptr[r0 + j] = base + rstart[j];
    for (int i = t; i < cnt; i += 256) {
        int pr = part_r[base + i];
        int pos = atomicAdd(&rcur[pr], 1);
        sedge[base + pos] = part_cv[base + i];
    }
}

// ---------- Frontier marking (backward pruning, bit-exact) ----------

__global__ void k_zero_flags(int* __restrict__ f, int words) {
    int i = blockIdx.x * blockDim.x + threadIdx.x;
    if (i < words) f[i] = 0;
}

__global__ void k_mark_batch(const int* __restrict__ user, const int* __restrict__ pos,
                             const int* __restrict__ neg, int NU, int NI, int B,
                             unsigned char* __restrict__ flag3,
                             unsigned char* __restrict__ flag2) {
    int b = blockIdx.x * blockDim.x + threadIdx.x;
    if (b >= B) return;
    int ui = min(max(user[b], 0), NU - 1);
    int pi = NU + min(max(pos[b], 0), NI - 1);
    int ni = NU + min(max(neg[b], 0), NI - 1);
    flag3[ui] = 1; flag3[pi] = 1; flag3[ni] = 1;
    flag2[ui] = 1; flag2[pi] = 1; flag2[ni] = 1;
}

__global__ void k_mark_nbrs(const int* __restrict__ row_ptr,
                            const unsigned int* __restrict__ sedge,
                            const unsigned char* __restrict__ flag3,
                            unsigned char* __restrict__ flag2, int N) {
    int r = blockIdx.x * blockDim.x + threadIdx.x;
    if (r >= N || !flag3[r]) return;
    int beg = row_ptr[r], end = row_ptr[r + 1];
    for (int i = beg; i < end; ++i)
        flag2[sedge[i] >> 14] = 1;
}

// ---------- SpMM (fp8 in / fp8 out, per-row scales) ----------

__global__ void k_spmm_csr8(const unsigned char* __restrict__ T,
                            const float* __restrict__ S,
                            unsigned char* __restrict__ Td,
                            float* __restrict__ Sd,
                            const int* __restrict__ row_ptr,
                            const unsigned int* __restrict__ sedge, int N,
                            const unsigned char* __restrict__ skipf, int use_skip) {
    int row = blockIdx.x * (blockDim.x >> 6) + (threadIdx.x >> 6);
    if (row >= N) return;
    if (use_skip && skipf[row] == 0) return;
    int lane = threadIdx.x & 63;
    int sub = lane >> 3;         // 0..7: edge phase
    int sl  = lane & 7;          // 16B chunk of the row
    int beg = row_ptr[row], end = row_ptr[row + 1];
    float a[16];
    #pragma unroll
    for (int j = 0; j < 16; ++j) a[j] = 0.0f;
    int i = beg + sub;
    for (; i + 8 < end; i += 16) {
        unsigned int se0 = sedge[i];
        unsigned int se1 = sedge[i + 8];
        unsigned int c0 = se0 >> 14, c1 = se1 >> 14;
        uint4 h0 = ((const uint4*)(T + (size_t)c0 * EMB_D))[sl];
        uint4 h1 = ((const uint4*)(T + (size_t)c1 * EMB_D))[sl];
        float vs0 = __uint_as_float((se0 & 0x3FFFu) << 17) * S[c0];
        float vs1 = __uint_as_float((se1 & 0x3FFFu) << 17) * S[c1];
        f32x2 d;
        d = cvt2_fp8(h0.x);       a[0] += vs0 * d.x;  a[1] += vs0 * d.y;
        d = cvt2_fp8(h0.x >> 16); a[2] += vs0 * d.x;  a[3] += vs0 * d.y;
        d = cvt2_fp8(h0.y);       a[4] += vs0 * d.x;  a[5] += vs0 * d.y;
        d = cvt2_fp8(h0.y >> 16); a[6] += vs0 * d.x;  a[7] += vs0 * d.y;
        d = cvt2_fp8(h0.z);       a[8] += vs0 * d.x;  a[9] += vs0 * d.y;
        d = cvt2_fp8(h0.z >> 16); a[10] += vs0 * d.x; a[11] += vs0 * d.y;
        d = cvt2_fp8(h0.w);       a[12] += vs0 * d.x; a[13] += vs0 * d.y;
        d = cvt2_fp8(h0.w >> 16); a[14] += vs0 * d.x; a[15] += vs0 * d.y;
        d = cvt2_fp8(h1.x);       a[0] += vs1 * d.x;  a[1] += vs1 * d.y;
        d = cvt2_fp8(h1.x >> 16); a[2] += vs1 * d.x;  a[3] += vs1 * d.y;
        d = cvt2_fp8(h1.y);       a[4] += vs1 * d.x;  a[5] += vs1 * d.y;
        d = cvt2_fp8(h1.y >> 16); a[6] += vs1 * d.x;  a[7] += vs1 * d.y;
        d = cvt2_fp8(h1.z);       a[8] += vs1 * d.x;  a[9] += vs1 * d.y;
        d = cvt2_fp8(h1.z >> 16); a[10] += vs1 * d.x; a[11] += vs1 * d.y;
        d = cvt2_fp8(h1.w);       a[12] += vs1 * d.x; a[13] += vs1 * d.y;
        d = cvt2_fp8(h1.w >> 16); a[14] += vs1 * d.x; a[15] += vs1 * d.y;
    }
    if (i < end) {
        unsigned int se = sedge[i];
        unsigned int c = se >> 14;
        uint4 h = ((const uint4*)(T + (size_t)c * EMB_D))[sl];
        float vs = __uint_as_float((se & 0x3FFFu) << 17) * S[c];
        f32x2 d;
        d = cvt2_fp8(h.x);       a[0] += vs * d.x;  a[1] += vs * d.y;
        d = cvt2_fp8(h.x >> 16); a[2] += vs * d.x;  a[3] += vs * d.y;
        d = cvt2_fp8(h.y);       a[4] += vs * d.x;  a[5] += vs * d.y;
        d = cvt2_fp8(h.y >> 16); a[6] += vs * d.x;  a[7] += vs * d.y;
        d = cvt2_fp8(h.z);       a[8] += vs * d.x;  a[9] += vs * d.y;
        d = cvt2_fp8(h.z >> 16); a[10] += vs * d.x; a[11] += vs * d.y;
        d = cvt2_fp8(h.w);       a[12] += vs * d.x; a[13] += vs * d.y;
        d = cvt2_fp8(h.w >> 16); a[14] += vs * d.x; a[15] += vs * d.y;
    }
    #pragma unroll
    for (int j = 0; j < 16; ++j) {
        a[j] += __shfl_xor(a[j], 8, 64);
        a[j] += __shfl_xor(a[j], 16, 64);
        a[j] += __shfl_xor(a[j], 32, 64);
    }
    float m = 0.0f;
    #pragma unroll
    for (int j = 0; j < 16; ++j) m = fmaxf(m, fabsf(a[j]));
    m = fmaxf(m, __shfl_xor(m, 1, 64));
    m = fmaxf(m, __shfl_xor(m, 2, 64));
    m = fmaxf(m, __shfl_xor(m, 4, 64));
    if (sub == 0) {
        float enc = (m > 0.0f) ? 448.0f / m : 0.0f;
        uint4 w;
        w.x = fp8x4_enc(a[0] * enc,  a[1] * enc,  a[2] * enc,  a[3] * enc);
        w.y = fp8x4_enc(a[4] * enc,  a[5] * enc,  a[6] * enc,  a[7] * enc);
        w.z = fp8x4_enc(a[8] * enc,  a[9] * enc,  a[10] * enc, a[11] * enc);
        w.w = fp8x4_enc(a[12] * enc, a[13] * enc, a[14] * enc, a[15] * enc);
        ((uint4*)(Td + (size_t)row * EMB_D))[sl] = w;
        if (lane == 0) Sd[row] = (m > 0.0f) ? m * (1.0f / 448.0f) : 0.0f;
    }
}

// Fused tail: gather layer0 (exact) + T1..T3 (fp8+scale) at batch nodes,
// dot, softplus, + reg. One block (128 thr) per batch element.
__global__ void k_gather_final(
        const void* __restrict__ ue, const void* __restrict__ ie,
        const int* __restrict__ flags,
        const int* __restrict__ user, const int* __restrict__ pos,
        const int* __restrict__ neg, int NU, int NI,
        const unsigned char* __restrict__ T1, const float* __restrict__ S1,
        const unsigned char* __restrict__ T2, const float* __restrict__ S2,
        const unsigned char* __restrict__ T3, const float* __restrict__ S3,
        const float* __restrict__ reg, float* __restrict__ out) {
    __shared__ float sps[2], sns[2];
    int b = blockIdx.x;
    int d = threadIdx.x;   // 0..127
    int ui = min(max(user[b], 0), NU - 1);
    int pi = min(max(pos[b],  0), NI - 1);
    int ni = min(max(neg[b],  0), NI - 1);
    size_t ru = (size_t)ui;
    size_t rp = (size_t)NU + pi;
    size_t rn = (size_t)NU + ni;
    int f0 = flags[0], f1 = flags[1];
    float u = sane(load_f(ue, f0, ru * EMB_D + d))
            + fp8_dec_byte(T1[ru * EMB_D + d]) * S1[ru]
            + fp8_dec_byte(T2[ru * EMB_D + d]) * S2[ru]
            + fp8_dec_byte(T3[ru * EMB_D + d]) * S3[ru];
    float p = sane(load_f(ie, f1, (size_t)pi * EMB_D + d))
            + fp8_dec_byte(T1[rp * EMB_D + d]) * S1[rp]
            + fp8_dec_byte(T2[rp * EMB_D + d]) * S2[rp]
            + fp8_dec_byte(T3[rp * EMB_D + d]) * S3[rp];
    float n = sane(load_f(ie, f1, (size_t)ni * EMB_D + d))
            + fp8_dec_byte(T1[rn * EMB_D + d]) * S1[rn]
            + fp8_dec_byte(T2[rn * EMB_D + d]) * S2[rn]
            + fp8_dec_byte(T3[rn * EMB_D + d]) * S3[rn];
    float ps = u * p, ns = u * n;
    #pragma unroll
    for (int off = 32; off > 0; off >>= 1) {
        ps += __shfl_down(ps, off, 64);
        ns += __shfl_down(ns, off, 64);
    }
    if ((d & 63) == 0) { sps[d >> 6] = ps; sns[d >> 6] = ns; }
    __syncthreads();
    if (d == 0) {
        // latents are acc/4 -> scores scale by 1/16
        float x = ((sns[0] + sns[1]) - (sps[0] + sps[1])) * 0.0625f;
        float sp = fmaxf(x, 0.0f) + log1pf(expf(-fabsf(x)));
        out[b] = sp + 1e-4f * reg[0];
    }
}

extern "C" void kernel_launch(void* const* d_in, const int* in_sizes, int n_in,
                              void* d_out, int out_size, void* d_ws, size_t ws_size,
                              hipStream_t stream) {
    const void* ue   = d_in[0];
    const void* ie   = d_in[1];
    const int*  erow = (const int*)d_in[2];
    const int*  ecol = (const int*)d_in[3];
    const void* ev   = d_in[4];
    const int*  user = (const int*)d_in[5];
    const int*  pos  = (const int*)d_in[6];
    const int*  neg  = (const int*)d_in[7];

    int NU = in_sizes[0] / EMB_D;        // 100000
    int NI = in_sizes[1] / EMB_D;        // 50000
    int N  = NU + NI;                    // 150000
    int E  = in_sizes[2];                // 2000000
    int B  = in_sizes[5];                // 8192

    int nbuck = (N + ((1 << BSH) - 1)) >> BSH;   // 293 (<= MAXBUCK)
    int NBp   = (E + CHUNKP - 1) / CHUNKP;       // 977 partition blocks
    int L     = nbuck * NBp;                     // 286261
    int nbL   = (L + 1023) / 1024;               // 280 (<= 1024)

    // Workspace layout (all 16B-aligned):
    size_t T8   = (size_t)N * EMB_D;                           // 19.2 MB (fp8)
    size_t SC   = (((size_t)N * sizeof(float)) + 15) & ~15ull; // 600 KB
    size_t NI4  = ((size_t)(N + 1) * sizeof(int) + 15) & ~15ull;
    size_t L4   = ((size_t)L * sizeof(int) + 15) & ~15ull;
    size_t E2   = (((size_t)E * 2) + 15) & ~15ull;             // u16 rows
    size_t Npad = ((size_t)N + 15) & ~15ull;
    char* w = (char*)d_ws;
    int*   flags   = (int*)w;                        // 3 ints
    float* reg     = (float*)(w + 64);               // 1 float
    char*  q       = w + 256;
    float* regp    = (float*)q;             q += (size_t)B * sizeof(float);
    int*   row_ptr = (int*)q;               q += NI4;
    unsigned int*   part_cv = (unsigned int*)q;   q += (size_t)E * 4;   // 8 MB
    unsigned short* part_r  = (unsigned short*)q; q += E2;              // 4 MB
    int*   bcnt    = (int*)q;               q += L4;                    // 1.15 MB
    int*   bsums   = (int*)q;               q += 4096;
    int*   boffs   = (int*)q;               q += 4096;
    unsigned char* flag3 = (unsigned char*)q; q += Npad;                // 150 KB
    unsigned char* flag2 = (unsigned char*)q; q += Npad;                // 150 KB
    unsigned int* sedge = (unsigned int*)q; q += (size_t)E * 4;         // 8 MB
    unsigned char* Ta = (unsigned char*)q;  q += T8;
    float*         Sa = (float*)q;          q += SC;
    unsigned char* T1 = (unsigned char*)q;  q += T8;
    float*         S1 = (float*)q;          q += SC;
    unsigned char* T2 = (unsigned char*)q;  q += T8;
    float*         S2 = (float*)q;          q += SC;
    unsigned char* T3 = (unsigned char*)q;  q += T8;
    float*         S3 = (float*)q;
    // total ~103 MB (prev session proved ws >= 166 MB)

    const int thr = 256;
    float* out = (float*)d_out;

    k_detect<<<3, 64, 0, stream>>>((const unsigned short*)ue, (const unsigned short*)ie,
                                   (const unsigned short*)ev, flags);
    k_build_emb8<<<(N * 32 + thr - 1) / thr, thr, 0, stream>>>(ue, ie, flags, Ta, Sa, NU, N);
    k_reg<<<B, EMB_D, 0, stream>>>(ue, ie, flags, user, pos, neg, NU, NI, regp);
    k_reduce_reg<<<1, 256, 0, stream>>>(regp, reg, B);

    // Frontier flags: flag3 = batch nodes; flag2 = batch + in-nbrs of flag3.
    int fwords = (int)((2 * Npad) / 4);
    k_zero_flags<<<(fwords + thr - 1) / thr, thr, 0, stream>>>((int*)flag3, fwords);
    k_mark_batch<<<(B + thr - 1) / thr, thr, 0, stream>>>(user, pos, neg, NU, NI, B,
                                                          flag3, flag2);

    // CSR build: two-level LDS partition, no global atomics.
    k_part_count<<<NBp, 256, 0, stream>>>(erow, bcnt, E, N, nbuck, NBp);
    k_gscan1<<<nbL, 256, 0, stream>>>(bcnt, bsums, L);
    k_gscan2<<<1, 256, 0, stream>>>(bsums, boffs, nbL, row_ptr + N);
    k_gscan3<<<nbL, 256, 0, stream>>>(bcnt, boffs, L);
    k_part_scatter<<<NBp, 256, 0, stream>>>(erow, ecol, ev, flags, bcnt,
                                            part_cv, part_r, E, N, nbuck, NBp);
    k_build_csr<<<nbuck, 256, 0, stream>>>(part_cv, part_r, bcnt, row_ptr, sedge,
                                           E, N, NBp, nbuck);

    // flag2 |= in-neighbors of flag3 rows (needs CSR).
    k_mark_nbrs<<<(N + thr - 1) / thr, thr, 0, stream>>>(row_ptr, sedge, flag3, flag2, N);

    int rows_per_block = thr / 64;                       // 4
    int sgrid = (N + rows_per_block - 1) / rows_per_block;  // 37500

    // Layer 1: Ta -> T1 (full)
    k_spmm_csr8<<<sgrid, thr, 0, stream>>>(Ta, Sa, T1, S1, row_ptr, sedge, N, flag2, 0);
    // Layer 2: T1 -> T2 (rows needed by layer 3 + batch)
    k_spmm_csr8<<<sgrid, thr, 0, stream>>>(T1, S1, T2, S2, row_ptr, sedge, N, flag2, 1);
    // Layer 3: T2 -> T3 (batch rows only)
    k_spmm_csr8<<<sgrid, thr, 0, stream>>>(T2, S2, T3, S3, row_ptr, sedge, N, flag3, 1);

    // Fused batch gather + dots + softplus + reg.
    k_gather_final<<<B, EMB_D, 0, stream>>>(ue, ie, flags, user, pos, neg, NU, NI,
                                            T1, S1, T2, S2, T3, S3, reg, out);
}

// Round 8
// 416.472 us; speedup vs baseline: 1.0914x; 1.0600x over previous
//
#include <hip/hip_runtime.h>
#include <hip/hip_bf16.h>

#define EMB_D 128
#define BSH 9          // rows per coarse bucket = 512
#define MAXBUCK 512    // nbuck = ceil(N/512) must be <= 512 (N <= 262144)
#define CHUNKP 2048    // edges per partition block (25 KB LDS -> ~6 blocks/CU)

typedef float f32x2 __attribute__((ext_vector_type(2)));

__device__ __forceinline__ float bf16_raw_to_f(unsigned short h) {
    return __uint_as_float(((unsigned int)h) << 16);
}
__device__ __forceinline__ float sane(float v) {
    return (v == v && fabsf(v) < 256.0f) ? v : 0.0f;
}
__device__ __forceinline__ float load_f(const void* p, int isf32, size_t idx) {
    return isf32 ? ((const float*)p)[idx]
                 : bf16_raw_to_f(((const unsigned short*)p)[idx]);
}

// ---------- fp8 e4m3fn via gfx950 HW converts (inline asm) ------
__device__ __forceinline__ f32x2 cvt2_fp8(unsigned int w) {
    f32x2 r;
    asm("v_cvt_pk_f32_fp8 %0, %1" : "=v"(r) : "v"(w));
    return r;
}
__device__ __forceinline__ unsigned int enc2_fp8(float a, float b) {
    unsigned int r;
    asm("v_cvt_pk_fp8_f32 %0, %1, %2" : "=v"(r) : "v"(a), "v"(b));
    return r & 0xFFFFu;
}
__device__ __forceinline__ unsigned int fp8x4_enc(float a, float b, float c, float d) {
    return enc2_fp8(a, b) | (enc2_fp8(c, d) << 16);
}
__device__ __forceinline__ float fp8_dec_byte(unsigned int b) {
    return cvt2_fp8(b & 0xFFu).x;
}

// flags[a]=1 if array a is stored fp32, 0 if bf16 (insurance; expect all 1).
__global__ void k_detect(const unsigned short* __restrict__ ue,
                         const unsigned short* __restrict__ ie,
                         const unsigned short* __restrict__ ev,
                         int* __restrict__ flags) {
    int a = blockIdx.x;
    const unsigned short* p = (a == 0) ? ue : (a == 1) ? ie : ev;
    int lane = threadIdx.x;
    int cnt = 0;
    #pragma unroll
    for (int k = 0; k < 16; ++k) {
        float v = bf16_raw_to_f(p[k * 64 + lane]);
        if (!(fabsf(v) < 1.0f)) cnt++;
    }
    #pragma unroll
    for (int off = 32; off > 0; off >>= 1)
        cnt += __shfl_down(cnt, off, 64);
    if (lane == 0) flags[a] = (cnt > 64) ? 1 : 0;
}

// Canonical fp8 table T[N,128] + per-row scale S[N]. 32 lanes per row.
__global__ __launch_bounds__(256) void k_build_emb8(
        const void* __restrict__ ue, const void* __restrict__ ie,
        const int* __restrict__ flags,
        unsigned char* __restrict__ T, float* __restrict__ S,
        int NU, int N) {
    int gid = blockIdx.x * blockDim.x + threadIdx.x;
    int row = gid >> 5;
    if (row >= N) return;
    int l = gid & 31;
    const void* src; long r; int f;
    if (row < NU) { src = ue; r = row;      f = flags[0]; }
    else          { src = ie; r = row - NU; f = flags[1]; }
    float v0, v1, v2, v3;
    if (f) {
        float4 t = ((const float4*)src)[r * 32 + l];
        v0 = sane(t.x); v1 = sane(t.y); v2 = sane(t.z); v3 = sane(t.w);
    } else {
        ushort4 t = ((const ushort4*)src)[r * 32 + l];
        v0 = sane(bf16_raw_to_f(t.x)); v1 = sane(bf16_raw_to_f(t.y));
        v2 = sane(bf16_raw_to_f(t.z)); v3 = sane(bf16_raw_to_f(t.w));
    }
    float m = fmaxf(fmaxf(fabsf(v0), fabsf(v1)), fmaxf(fabsf(v2), fabsf(v3)));
    #pragma unroll
    for (int off = 1; off < 32; off <<= 1)
        m = fmaxf(m, __shfl_xor(m, off, 64));
    float enc = (m > 0.0f) ? 448.0f / m : 0.0f;
    ((unsigned int*)T)[(size_t)row * 32 + l] =
        fp8x4_enc(v0 * enc, v1 * enc, v2 * enc, v3 * enc);
    if (l == 0) S[row] = (m > 0.0f) ? m * (1.0f / 448.0f) : 0.0f;
}

// Reduce regp[B] -> reg[0]. Single block.
__global__ void k_reduce_reg(const float* __restrict__ regp, float* __restrict__ reg, int B) {
    __shared__ float ss[256];
    int t = threadIdx.x;
    float s = 0.0f;
    for (int i = t; i < B; i += 256) s += regp[i];
    ss[t] = s;
    __syncthreads();
    for (int off = 128; off > 0; off >>= 1) {
        if (t < off) ss[t] += ss[t + off];
        __syncthreads();
    }
    if (t == 0) reg[0] = ss[0];
}

// ---------- CSR build, transaction-efficient two-level partition ----------

__global__ __launch_bounds__(256) void k_part_count(const int* __restrict__ erow,
        int* __restrict__ bcnt, int E, int N, int nbuck, int NB) {
    __shared__ int lh[MAXBUCK];
    int b = blockIdx.x, t = threadIdx.x;
    for (int i = t; i < MAXBUCK; i += 256) lh[i] = 0;
    __syncthreads();
    int beg = b * CHUNKP;
    int cnt = min(CHUNKP, E - beg);
    for (int p = t; p < cnt; p += 256) {
        int r = min(max(erow[beg + p], 0), N - 1);
        atomicAdd(&lh[r >> BSH], 1);
    }
    __syncthreads();
    for (int i = t; i < nbuck; i += 256) bcnt[(long)i * NB + b] = lh[i];
}

// Generic 3-phase exclusive scan over int array a[L] (in place).
__global__ void k_gscan1(const int* __restrict__ a, int* __restrict__ bsums, int L) {
    __shared__ int ss[256];
    int t = threadIdx.x;
    int base = blockIdx.x * 1024 + t * 4;
    int s = 0;
    #pragma unroll
    for (int j = 0; j < 4; ++j) {
        int idx = base + j;
        if (idx < L) s += a[idx];
    }
    ss[t] = s;
    __syncthreads();
    for (int off = 128; off > 0; off >>= 1) {
        if (t < off) ss[t] += ss[t + off];
        __syncthreads();
    }
    if (t == 0) bsums[blockIdx.x] = ss[0];
}

// Single block scans nb (<=1024) block sums, 4 per thread.
__global__ void k_gscan2(const int* __restrict__ bsums, int* __restrict__ boffs,
                         int nb, int* __restrict__ rowptrN) {
    __shared__ int ss[256];
    int t = threadIdx.x;
    int base = t * 4;
    int c[4];
    int s = 0;
    #pragma unroll
    for (int j = 0; j < 4; ++j) {
        c[j] = (base + j < nb) ? bsums[base + j] : 0;
        s += c[j];
    }
    ss[t] = s;
    __syncthreads();
    for (int off = 1; off < 256; off <<= 1) {
        int v = (t >= off) ? ss[t - off] : 0;
        __syncthreads();
        ss[t] += v;
        __syncthreads();
    }
    int run = ss[t] - s;
    #pragma unroll
    for (int j = 0; j < 4; ++j) {
        if (base + j < nb) boffs[base + j] = run;
        run += c[j];
    }
    if (t == 255) *rowptrN = ss[255];       // total E -> row_ptr[N]
}

__global__ void k_gscan3(int* __restrict__ a, const int* __restrict__ boffs, int L) {
    __shared__ int ss[256];
    int t = threadIdx.x;
    int base = blockIdx.x * 1024 + t * 4;
    int c[4];
    int s = 0;
    #pragma unroll
    for (int j = 0; j < 4; ++j) {
        int idx = base + j;
        c[j] = (idx < L) ? a[idx] : 0;
        s += c[j];
    }
    ss[t] = s;
    __syncthreads();
    for (int off = 1; off < 256; off <<= 1) {
        int v = (t >= off) ? ss[t - off] : 0;
        __syncthreads();
        ss[t] += v;
        __syncthreads();
    }
    int run = boffs[blockIdx.x] + ss[t] - s;
    #pragma unroll
    for (int j = 0; j < 4; ++j) {
        int idx = base + j;
        if (idx < L) a[idx] = run;
        run += c[j];
    }
}

// Pass B: counting-sort CHUNKP edges by dst bucket in LDS, stream out
// split records: part_cv (col<<14|val14, u32) + part_r (row & 511, u16).
__global__ __launch_bounds__(256) void k_part_scatter(
        const int* __restrict__ erow, const int* __restrict__ ecol,
        const void* __restrict__ eval, const int* __restrict__ flags,
        const int* __restrict__ boff,
        unsigned int* __restrict__ part_cv, unsigned short* __restrict__ part_r,
        int E, int N, int nbuck, int NB) {
    __shared__ uint2 lrec[CHUNKP];            // 16 KB
    __shared__ unsigned short lidx[CHUNKP];   // 4 KB
    __shared__ int hist[MAXBUCK];             // 2 KB (hist -> cursor -> delta)
    __shared__ int bstart[MAXBUCK];           // 2 KB
    __shared__ int ss[256];
    int b = blockIdx.x, t = threadIdx.x;
    int beg = b * CHUNKP;
    int cnt = min(CHUNKP, E - beg);
    for (int i = t; i < MAXBUCK; i += 256) hist[i] = 0;
    __syncthreads();
    int f2 = flags[2];
    for (int p = t; p < cnt; p += 256) {
        int e = beg + p;
        int r = min(max(erow[e], 0), N - 1);
        int c = min(max(ecol[e], 0), N - 1);
        float v = sane(load_f(eval, f2, e));
        if (v < 0.0f) v = 0.0f;
        unsigned int u = __float_as_uint(v);
        unsigned int vb = ((u + 0x10000u) >> 17) & 0x3FFFu;   // exp8 + man6
        lrec[p] = make_uint2((unsigned int)r, ((unsigned int)c << 14) | vb);
        atomicAdd(&hist[r >> BSH], 1);
    }
    __syncthreads();
    int c0 = hist[2 * t], c1 = hist[2 * t + 1];
    int s = c0 + c1;
    ss[t] = s;
    __syncthreads();
    for (int off = 1; off < 256; off <<= 1) {
        int v = (t >= off) ? ss[t - off] : 0;
        __syncthreads();
        ss[t] += v;
        __syncthreads();
    }
    int eb = ss[t] - s;
    bstart[2 * t] = eb;
    bstart[2 * t + 1] = eb + c0;
    hist[2 * t] = eb;              // cursor = bstart
    hist[2 * t + 1] = eb + c0;
    __syncthreads();
    for (int p = t; p < cnt; p += 256) {
        int bin = (int)(lrec[p].x >> BSH);
        int pos = atomicAdd(&hist[bin], 1);
        lidx[pos] = (unsigned short)p;
    }
    __syncthreads();
    for (int i = t; i < nbuck; i += 256)
        hist[i] = boff[(long)i * NB + b] - bstart[i];
    __syncthreads();
    for (int p = t; p < cnt; p += 256) {
        uint2 rec = lrec[lidx[p]];
        int bin = (int)(rec.x >> BSH);
        int o = hist[bin] + p;
        part_cv[o] = rec.y;
        part_r[o] = (unsigned short)(rec.x & 511u);
    }
}

// Pass C: one block per bucket (<=512 rows, L2-resident window).
__global__ __launch_bounds__(256) void k_build_csr(
        const unsigned int* __restrict__ part_cv,
        const unsigned short* __restrict__ part_r,
        const int* __restrict__ boff,
        int* __restrict__ row_ptr, unsigned int* __restrict__ sedge,
        int E, int N, int NB, int nbuck) {
    __shared__ int rcnt[512];
    __shared__ int rstart[512];
    __shared__ int rcur[512];
    __shared__ int ss[256];
    int bin = blockIdx.x, t = threadIdx.x;
    int base = boff[(long)bin * NB];
    int next = (bin + 1 < nbuck) ? boff[(long)(bin + 1) * NB] : E;
    int cnt = next - base;
    int r0 = bin << BSH;
    int nrows = min(512, N - r0);
    rcnt[2 * t] = 0; rcnt[2 * t + 1] = 0;
    __syncthreads();
    for (int i = t; i < cnt; i += 256)
        atomicAdd(&rcnt[part_r[base + i]], 1);
    __syncthreads();
    int c0 = rcnt[2 * t], c1 = rcnt[2 * t + 1];
    int s = c0 + c1;
    ss[t] = s;
    __syncthreads();
    for (int off = 1; off < 256; off <<= 1) {
        int v = (t >= off) ? ss[t - off] : 0;
        __syncthreads();
        ss[t] += v;
        __syncthreads();
    }
    int eb = ss[t] - s;
    rstart[2 * t] = eb; rstart[2 * t + 1] = eb + c0;
    rcur[2 * t]   = eb; rcur[2 * t + 1]   = eb + c0;
    __syncthreads();
    for (int j = t; j < nrows; j += 256)
        row_ptr[r0 + j] = base + rstart[j];
    for (int i = t; i < cnt; i += 256) {
        int pr = part_r[base + i];
        int pos = atomicAdd(&rcur[pr], 1);
        sedge[base + pos] = part_cv[base + i];
    }
}

// ---------- Frontier marking (backward pruning, bit-exact) ----------

__global__ void k_zero_flags(int* __restrict__ f, int words) {
    int i = blockIdx.x * blockDim.x + threadIdx.x;
    if (i < words) f[i] = 0;
}

__global__ void k_mark_batch(const int* __restrict__ user, const int* __restrict__ pos,
                             const int* __restrict__ neg, int NU, int NI, int B,
                             unsigned char* __restrict__ flag3,
                             unsigned char* __restrict__ flag2) {
    int b = blockIdx.x * blockDim.x + threadIdx.x;
    if (b >= B) return;
    int ui = min(max(user[b], 0), NU - 1);
    int pi = NU + min(max(pos[b], 0), NI - 1);
    int ni = NU + min(max(neg[b], 0), NI - 1);
    flag3[ui] = 1; flag3[pi] = 1; flag3[ni] = 1;
    flag2[ui] = 1; flag2[pi] = 1; flag2[ni] = 1;
}

// Edge-parallel: flag2 |= {col : row in flag3}. Uses original edge list
// (same clamps as CSR build), no CSR dependency, streaming reads.
__global__ void k_mark_nbrs_e(const int* __restrict__ erow, const int* __restrict__ ecol,
                              const unsigned char* __restrict__ flag3,
                              unsigned char* __restrict__ flag2, int E, int N) {
    int e = blockIdx.x * blockDim.x + threadIdx.x;
    if (e >= E) return;
    int r = min(max(erow[e], 0), N - 1);
    if (flag3[r]) {
        int c = min(max(ecol[e], 0), N - 1);
        flag2[c] = 1;
    }
}

// ---------- SpMM (fp8 in / fp8 out, per-row scales) ----------
// One wave per dst row; 4 phase-groups of 16 lanes each process every 4th
// edge; lane sl covers fp8 bytes [8*sl, 8*sl+7] (one uint2) of the 128B row.
// Pair-unrolled (edges i, i+4 in flight together).
__global__ void k_spmm_csr8(const unsigned char* __restrict__ T,
                            const float* __restrict__ S,
                            unsigned char* __restrict__ Td,
                            float* __restrict__ Sd,
                            const int* __restrict__ row_ptr,
                            const unsigned int* __restrict__ sedge, int N,
                            const unsigned char* __restrict__ skipf, int use_skip) {
    int row = blockIdx.x * (blockDim.x >> 6) + (threadIdx.x >> 6);
    if (row >= N) return;
    if (use_skip && skipf[row] == 0) return;
    int lane = threadIdx.x & 63;
    int ph = lane >> 4;          // 0..3: edge phase
    int sl = lane & 15;          // 8B chunk of the row
    int beg = row_ptr[row], end = row_ptr[row + 1];
    float a[8];
    #pragma unroll
    for (int j = 0; j < 8; ++j) a[j] = 0.0f;
    int i = beg + ph;
    for (; i + 4 < end; i += 8) {     // pair: edges i and i+4
        unsigned int se0 = sedge[i];
        unsigned int se1 = sedge[i + 4];
        unsigned int c0 = se0 >> 14, c1 = se1 >> 14;
        uint2 h0 = ((const uint2*)(T + (size_t)c0 * EMB_D))[sl];
        uint2 h1 = ((const uint2*)(T + (size_t)c1 * EMB_D))[sl];
        float vs0 = __uint_as_float((se0 & 0x3FFFu) << 17) * S[c0];
        float vs1 = __uint_as_float((se1 & 0x3FFFu) << 17) * S[c1];
        f32x2 d;
        d = cvt2_fp8(h0.x);       a[0] += vs0 * d.x; a[1] += vs0 * d.y;
        d = cvt2_fp8(h0.x >> 16); a[2] += vs0 * d.x; a[3] += vs0 * d.y;
        d = cvt2_fp8(h0.y);       a[4] += vs0 * d.x; a[5] += vs0 * d.y;
        d = cvt2_fp8(h0.y >> 16); a[6] += vs0 * d.x; a[7] += vs0 * d.y;
        d = cvt2_fp8(h1.x);       a[0] += vs1 * d.x; a[1] += vs1 * d.y;
        d = cvt2_fp8(h1.x >> 16); a[2] += vs1 * d.x; a[3] += vs1 * d.y;
        d = cvt2_fp8(h1.y);       a[4] += vs1 * d.x; a[5] += vs1 * d.y;
        d = cvt2_fp8(h1.y >> 16); a[6] += vs1 * d.x; a[7] += vs1 * d.y;
    }
    if (i < end) {
        unsigned int se = sedge[i];
        unsigned int c = se >> 14;
        uint2 h = ((const uint2*)(T + (size_t)c * EMB_D))[sl];
        float vs = __uint_as_float((se & 0x3FFFu) << 17) * S[c];
        f32x2 d;
        d = cvt2_fp8(h.x);       a[0] += vs * d.x; a[1] += vs * d.y;
        d = cvt2_fp8(h.x >> 16); a[2] += vs * d.x; a[3] += vs * d.y;
        d = cvt2_fp8(h.y);       a[4] += vs * d.x; a[5] += vs * d.y;
        d = cvt2_fp8(h.y >> 16); a[6] += vs * d.x; a[7] += vs * d.y;
    }
    // reduce over the 4 phases (lanes xor 16, 32)
    #pragma unroll
    for (int j = 0; j < 8; ++j) {
        a[j] += __shfl_xor(a[j], 16, 64);
        a[j] += __shfl_xor(a[j], 32, 64);
    }
    // row absmax: local over 8, then across sl (xor 1,2,4,8)
    float m = fmaxf(fmaxf(fmaxf(fabsf(a[0]), fabsf(a[1])), fmaxf(fabsf(a[2]), fabsf(a[3]))),
                    fmaxf(fmaxf(fabsf(a[4]), fabsf(a[5])), fmaxf(fabsf(a[6]), fabsf(a[7]))));
    m = fmaxf(m, __shfl_xor(m, 1, 64));
    m = fmaxf(m, __shfl_xor(m, 2, 64));
    m = fmaxf(m, __shfl_xor(m, 4, 64));
    m = fmaxf(m, __shfl_xor(m, 8, 64));
    if (ph == 0) {
        float enc = (m > 0.0f) ? 448.0f / m : 0.0f;
        uint2 w;
        w.x = fp8x4_enc(a[0] * enc, a[1] * enc, a[2] * enc, a[3] * enc);
        w.y = fp8x4_enc(a[4] * enc, a[5] * enc, a[6] * enc, a[7] * enc);
        ((uint2*)(Td + (size_t)row * EMB_D))[sl] = w;
        if (lane == 0) Sd[row] = (m > 0.0f) ? m * (1.0f / 448.0f) : 0.0f;
    }
}

// Fused tail: gather layer0 (exact) + T1..T3 (fp8+scale) at batch nodes,
// dot + L1-reg partial. One block (128 thr) per batch element.
__global__ void k_gather_final(
        const void* __restrict__ ue, const void* __restrict__ ie,
        const int* __restrict__ flags,
        const int* __restrict__ user, const int* __restrict__ pos,
        const int* __restrict__ neg, int NU, int NI,
        const unsigned char* __restrict__ T1, const float* __restrict__ S1,
        const unsigned char* __restrict__ T2, const float* __restrict__ S2,
        const unsigned char* __restrict__ T3, const float* __restrict__ S3,
        float* __restrict__ xv, float* __restrict__ regp) {
    __shared__ float sps[2], sns[2], srg[2];
    int b = blockIdx.x;
    int d = threadIdx.x;   // 0..127
    int ui = min(max(user[b], 0), NU - 1);
    int pi = min(max(pos[b],  0), NI - 1);
    int ni = min(max(neg[b],  0), NI - 1);
    size_t ru = (size_t)ui;
    size_t rp = (size_t)NU + pi;
    size_t rn = (size_t)NU + ni;
    int f0 = flags[0], f1 = flags[1];
    float u0 = sane(load_f(ue, f0, ru * EMB_D + d));
    float p0 = sane(load_f(ie, f1, (size_t)pi * EMB_D + d));
    float n0 = sane(load_f(ie, f1, (size_t)ni * EMB_D + d));
    float u = u0
            + fp8_dec_byte(T1[ru * EMB_D + d]) * S1[ru]
            + fp8_dec_byte(T2[ru * EMB_D + d]) * S2[ru]
            + fp8_dec_byte(T3[ru * EMB_D + d]) * S3[ru];
    float p = p0
            + fp8_dec_byte(T1[rp * EMB_D + d]) * S1[rp]
            + fp8_dec_byte(T2[rp * EMB_D + d]) * S2[rp]
            + fp8_dec_byte(T3[rp * EMB_D + d]) * S3[rp];
    float n = n0
            + fp8_dec_byte(T1[rn * EMB_D + d]) * S1[rn]
            + fp8_dec_byte(T2[rn * EMB_D + d]) * S2[rn]
            + fp8_dec_byte(T3[rn * EMB_D + d]) * S3[rn];
    float ps = u * p, ns = u * n;
    float rg = fabsf(u0) + fabsf(p0) + fabsf(n0);
    #pragma unroll
    for (int off = 32; off > 0; off >>= 1) {
        ps += __shfl_down(ps, off, 64);
        ns += __shfl_down(ns, off, 64);
        rg += __shfl_down(rg, off, 64);
    }
    if ((d & 63) == 0) { sps[d >> 6] = ps; sns[d >> 6] = ns; srg[d >> 6] = rg; }
    __syncthreads();
    if (d == 0) {
        // latents are acc/4 -> scores scale by 1/16
        xv[b] = ((sns[0] + sns[1]) - (sps[0] + sps[1])) * 0.0625f;
        regp[b] = srg[0] + srg[1];
    }
}

// out[b] = softplus(xv[b]) + REG * reg_total
__global__ void k_final_out(const float* __restrict__ xv, const float* __restrict__ reg,
                            float* __restrict__ out, int B) {
    int b = blockIdx.x * blockDim.x + threadIdx.x;
    if (b >= B) return;
    float x = xv[b];
    float sp = fmaxf(x, 0.0f) + log1pf(expf(-fabsf(x)));
    out[b] = sp + 1e-4f * reg[0];
}

extern "C" void kernel_launch(void* const* d_in, const int* in_sizes, int n_in,
                              void* d_out, int out_size, void* d_ws, size_t ws_size,
                              hipStream_t stream) {
    const void* ue   = d_in[0];
    const void* ie   = d_in[1];
    const int*  erow = (const int*)d_in[2];
    const int*  ecol = (const int*)d_in[3];
    const void* ev   = d_in[4];
    const int*  user = (const int*)d_in[5];
    const int*  pos  = (const int*)d_in[6];
    const int*  neg  = (const int*)d_in[7];

    int NU = in_sizes[0] / EMB_D;        // 100000
    int NI = in_sizes[1] / EMB_D;        // 50000
    int N  = NU + NI;                    // 150000
    int E  = in_sizes[2];                // 2000000
    int B  = in_sizes[5];                // 8192

    int nbuck = (N + ((1 << BSH) - 1)) >> BSH;   // 293 (<= MAXBUCK)
    int NBp   = (E + CHUNKP - 1) / CHUNKP;       // 977 partition blocks
    int L     = nbuck * NBp;                     // 286261
    int nbL   = (L + 1023) / 1024;               // 280 (<= 1024)

    // Workspace layout (all 16B-aligned):
    size_t T8   = (size_t)N * EMB_D;                           // 19.2 MB (fp8)
    size_t SC   = (((size_t)N * sizeof(float)) + 15) & ~15ull; // 600 KB
    size_t NI4  = ((size_t)(N + 1) * sizeof(int) + 15) & ~15ull;
    size_t L4   = ((size_t)L * sizeof(int) + 15) & ~15ull;
    size_t E2   = (((size_t)E * 2) + 15) & ~15ull;             // u16 rows
    size_t Npad = ((size_t)N + 15) & ~15ull;
    char* w = (char*)d_ws;
    int*   flags   = (int*)w;                        // 3 ints
    float* reg     = (float*)(w + 64);               // 1 float
    char*  q       = w + 256;
    float* regp    = (float*)q;             q += (size_t)B * sizeof(float);
    float* xv      = (float*)q;             q += (size_t)B * sizeof(float);
    int*   row_ptr = (int*)q;               q += NI4;
    unsigned int*   part_cv = (unsigned int*)q;   q += (size_t)E * 4;   // 8 MB
    unsigned short* part_r  = (unsigned short*)q; q += E2;              // 4 MB
    int*   bcnt    = (int*)q;               q += L4;                    // 1.15 MB
    int*   bsums   = (int*)q;               q += 4096;
    int*   boffs   = (int*)q;               q += 4096;
    unsigned char* flag3 = (unsigned char*)q; q += Npad;                // 150 KB
    unsigned char* flag2 = (unsigned char*)q; q += Npad;                // 150 KB
    unsigned int* sedge = (unsigned int*)q; q += (size_t)E * 4;         // 8 MB
    unsigned char* Ta = (unsigned char*)q;  q += T8;
    float*         Sa = (float*)q;          q += SC;
    unsigned char* T1 = (unsigned char*)q;  q += T8;
    float*         S1 = (float*)q;          q += SC;
    unsigned char* T2 = (unsigned char*)q;  q += T8;
    float*         S2 = (float*)q;          q += SC;
    unsigned char* T3 = (unsigned char*)q;  q += T8;
    float*         S3 = (float*)q;
    // total ~103 MB (prev session proved ws >= 166 MB)

    const int thr = 256;
    float* out = (float*)d_out;

    k_detect<<<3, 64, 0, stream>>>((const unsigned short*)ue, (const unsigned short*)ie,
                                   (const unsigned short*)ev, flags);
    k_build_emb8<<<(N * 32 + thr - 1) / thr, thr, 0, stream>>>(ue, ie, flags, Ta, Sa, NU, N);

    // Frontier flags: flag3 = batch nodes; flag2 = batch + in-nbrs of flag3.
    int fwords = (int)((2 * Npad) / 4);
    k_zero_flags<<<(fwords + thr - 1) / thr, thr, 0, stream>>>((int*)flag3, fwords);
    k_mark_batch<<<(B + thr - 1) / thr, thr, 0, stream>>>(user, pos, neg, NU, NI, B,
                                                          flag3, flag2);
    k_mark_nbrs_e<<<(E + thr - 1) / thr, thr, 0, stream>>>(erow, ecol, flag3, flag2, E, N);

    // CSR build: two-level LDS partition, no global atomics.
    k_part_count<<<NBp, 256, 0, stream>>>(erow, bcnt, E, N, nbuck, NBp);
    k_gscan1<<<nbL, 256, 0, stream>>>(bcnt, bsums, L);
    k_gscan2<<<1, 256, 0, stream>>>(bsums, boffs, nbL, row_ptr + N);
    k_gscan3<<<nbL, 256, 0, stream>>>(bcnt, boffs, L);
    k_part_scatter<<<NBp, 256, 0, stream>>>(erow, ecol, ev, flags, bcnt,
                                            part_cv, part_r, E, N, nbuck, NBp);
    k_build_csr<<<nbuck, 256, 0, stream>>>(part_cv, part_r, bcnt, row_ptr, sedge,
                                           E, N, NBp, nbuck);

    int rows_per_block = thr / 64;                       // 4
    int sgrid = (N + rows_per_block - 1) / rows_per_block;  // 37500

    // Layer 1: Ta -> T1 (full)
    k_spmm_csr8<<<sgrid, thr, 0, stream>>>(Ta, Sa, T1, S1, row_ptr, sedge, N, flag2, 0);
    // Layer 2: T1 -> T2 (rows needed by layer 3 + batch)
    k_spmm_csr8<<<sgrid, thr, 0, stream>>>(T1, S1, T2, S2, row_ptr, sedge, N, flag2, 1);
    // Layer 3: T2 -> T3 (batch rows only)
    k_spmm_csr8<<<sgrid, thr, 0, stream>>>(T2, S2, T3, S3, row_ptr, sedge, N, flag3, 1);

    // Fused batch gather + dots + reg partials, then scalar epilogue.
    k_gather_final<<<B, EMB_D, 0, stream>>>(ue, ie, flags, user, pos, neg, NU, NI,
                                            T1, S1, T2, S2, T3, S3, xv, regp);
    k_reduce_reg<<<1, 256, 0, stream>>>(regp, reg, B);
    k_final_out<<<(B + thr - 1) / thr, thr, 0, stream>>>(xv, reg, out, B);
}